// Round 5
// baseline (108.454 us; speedup 1.0000x reference)
//
#include <hip/hip_runtime.h>
#include <math.h>

#define NN 1024
#define HH 128

typedef _Float16 h2 __attribute__((ext_vector_type(2)));
typedef _Float16 h4 __attribute__((ext_vector_type(4)));
typedef _Float16 h8 __attribute__((ext_vector_type(8)));

__device__ inline float fdot2(h2 a, h2 b, float c) {
  return __builtin_amdgcn_fdot2(a, b, c, false);
}

// ---------------------------------------------------------------- qkv ------
// grid 257 x 512. Blocks 0..255: 4 rows, mat = t>>7 in {q,k,v,P}.
// P[j] = x[j] @ We1  (NO bias; bias folded on the i-side in attn).
// KP layout: [HH/2][NN/2] h8 blocks (16 B):
//   halves 0..3 = {K[j0][c0],K[j0][c1],K[j1][c0],K[j1][c1]}
//   halves 4..7 = {P[j0][c0],P[j0][c1],P[j1][c0],P[j1][c1]}   (j0=2*j2, c0=2*u)
// VP layout: [NN/4][HH/2] h8 blocks:
//   {V[j0][c0],V[j1][c0],V[j0][c1],V[j1][c1],V[j2][c0],V[j3][c0],V[j2][c1],V[j3][c1]}
// q is written pre-scaled by 1/sqrt(128).
// Block 256: Wc2/bc2 fold.
__global__ __launch_bounds__(512) void qkv_kernel(
    const float* __restrict__ h, const float* __restrict__ x,
    const float* __restrict__ Wq, const float* __restrict__ bq,
    const float* __restrict__ Wk, const float* __restrict__ bk,
    const float* __restrict__ Wv, const float* __restrict__ bv,
    const float* __restrict__ We1,
    const float* __restrict__ We2, const float* __restrict__ be2,
    const float* __restrict__ Wc, const float* __restrict__ bc,
    float* __restrict__ q, _Float16* __restrict__ KP,
    _Float16* __restrict__ VP, float* __restrict__ Wc2,
    float* __restrict__ bc2) {
  const int t = threadIdx.x;

  if (blockIdx.x == 256) {  // ---- wc2 fold ----
    if (t < HH) {
      float a = 0.f;
      for (int d = 0; d < HH; ++d) a = fmaf(We2[t * HH + d], Wc[d], a);
      Wc2[t] = a;
      if (t == 0) {
        float b = bc[0];
        for (int d = 0; d < HH; ++d) b = fmaf(be2[d], Wc[d], b);
        *bc2 = b;
      }
    }
    return;
  }

  __shared__ float4 hs4[HH];
  __shared__ float xsh[8];
  const int r0 = blockIdx.x * 4;
  if (t < HH) {
    hs4[t] = make_float4(h[(r0 + 0) * HH + t], h[(r0 + 1) * HH + t],
                         h[(r0 + 2) * HH + t], h[(r0 + 3) * HH + t]);
  }
  if (t >= HH && t < HH + 8) xsh[t - HH] = x[r0 * 2 + (t - HH)];
  __syncthreads();

  const int mat = t >> 7;  // 0=q 1=k 2=v 3=P
  const int col = t & 127;

  if (mat == 3) {  // ---- P = x @ We1 (f32, round once to f16) ----
    const float w0 = We1[col], w1 = We1[HH + col];
    const int base = ((col >> 1) * (NN / 2) + (r0 >> 1)) * 8 + 4 + (col & 1);
#pragma unroll
    for (int rr = 0; rr < 4; ++rr) {
      float p = fmaf(xsh[2 * rr], w0, xsh[2 * rr + 1] * w1);
      KP[base + (rr >> 1) * 8 + (rr & 1) * 2] = (_Float16)p;
    }
    return;
  }

  const float* W = (mat == 0) ? Wq : (mat == 1) ? Wk : Wv;
  const float* B = (mat == 0) ? bq : (mat == 1) ? bk : bv;
  const float b = B[col];
  float a0 = b, a1 = b, a2 = b, a3 = b;
#pragma unroll 16
  for (int c = 0; c < HH; ++c) {
    float w = W[c * HH + col];
    float4 hv = hs4[c];
    a0 = fmaf(hv.x, w, a0);
    a1 = fmaf(hv.y, w, a1);
    a2 = fmaf(hv.z, w, a2);
    a3 = fmaf(hv.w, w, a3);
  }
  if (mat == 0) {
    const float scale = 0.08838834764831845f;  // 1/sqrt(128) folded into q
    q[(r0 + 0) * HH + col] = a0 * scale;
    q[(r0 + 1) * HH + col] = a1 * scale;
    q[(r0 + 2) * HH + col] = a2 * scale;
    q[(r0 + 3) * HH + col] = a3 * scale;
  } else if (mat == 1) {
    const int base = ((col >> 1) * (NN / 2) + (r0 >> 1)) * 8 + (col & 1);
    KP[base + 0] = (_Float16)a0;   // rr=0
    KP[base + 2] = (_Float16)a1;   // rr=1
    KP[base + 8] = (_Float16)a2;   // rr=2
    KP[base + 10] = (_Float16)a3;  // rr=3
  } else {
    const int base = ((r0 >> 2) * (HH / 2) + (col >> 1)) * 8 + (col & 1) * 2;
    VP[base + 0] = (_Float16)a0;  // rr=0
    VP[base + 1] = (_Float16)a1;  // rr=1
    VP[base + 4] = (_Float16)a2;  // rr=2
    VP[base + 5] = (_Float16)a3;  // rr=3
  }
}

// ------------------------------------------------------------- attn --------
// grid 256 x 512; block = FOUR query rows (halves total KP/VP L2 traffic vs
// 2-row blocks); thread t owns j in {2t, 2t+1} and all 4 rows: 8 (i,j) pairs
// per 16B KP load — 2x compute per byte. 8-deep register prefetch kept.
// Barrier-free phase1->phase2 (wave consumes only its own wspi range);
// agg_h accumulates unnormalized, 1/sum applied after the single barrier.
__global__ __launch_bounds__(512) void attn_kernel(
    const float* __restrict__ h, const float* __restrict__ x,
    const float* __restrict__ q, const h8* __restrict__ KP,
    const h8* __restrict__ VP, const float* __restrict__ be1,
    const float* __restrict__ Wc2p, const float* __restrict__ bc2p,
    float* __restrict__ out) {
  __shared__ h8 qps[2][HH / 2];  // set s: {q_iA cpair, q_iB cpair, P'_iA, P'_iB}
  __shared__ h2 ccs[HH / 2];     // Wc2 cpair
  __shared__ h4 wspA[NN / 2];    // (e r0j0, e r0j1, e r1j0, e r1j1) per j2
  __shared__ h4 wspB[NN / 2];    // rows 2,3
  __shared__ float xs[NN * 2];
  __shared__ float part[8][4][HH];
  __shared__ float red[12][8];

  const int i0 = blockIdx.x * 4;
  const int tid = threadIdx.x;
  const int lane = tid & 63, wave = tid >> 6;  // 8 waves

  if (tid < HH) {  // 128 threads: s = row-set (0:rows01, 1:rows23), u = cpair
    const int s = tid >> 6, u = tid & 63;
    const int iA = i0 + 2 * s, iB = iA + 1;
    float2 qa = *(const float2*)(q + iA * HH + 2 * u);
    float2 qb = *(const float2*)(q + iB * HH + 2 * u);
    h8 kp = KP[u * (NN / 2) + (iA >> 1)];  // halves 4..7 = P rows iA,iB
    float2 b1 = *(const float2*)(be1 + 2 * u);
    h8 a;
    a[0] = (_Float16)qa.x; a[1] = (_Float16)qa.y;
    a[2] = (_Float16)qb.x; a[3] = (_Float16)qb.y;
    a[4] = (_Float16)((float)kp[4] + b1.x);
    a[5] = (_Float16)((float)kp[5] + b1.y);
    a[6] = (_Float16)((float)kp[6] + b1.x);
    a[7] = (_Float16)((float)kp[7] + b1.y);
    qps[s][u] = a;
    if (s == 0) {
      h2 c;
      c.x = (_Float16)Wc2p[2 * u];
      c.y = (_Float16)Wc2p[2 * u + 1];
      ccs[u] = c;
    }
  }
  for (int j = tid; j < NN * 2; j += 512) xs[j] = x[j];
  const float bc2 = *bc2p;
  __syncthreads();

  // coords: 4 query rows + this thread's 2 j columns (f32, for delta_x)
  float xix[4], xiy[4];
#pragma unroll
  for (int r = 0; r < 4; ++r) {
    xix[r] = xs[2 * (i0 + r)];
    xiy[r] = xs[2 * (i0 + r) + 1];
  }
  const int j0 = 2 * tid, j1 = j0 + 1;
  const float xj0x = xs[2 * j0], xj0y = xs[2 * j0 + 1];
  const float xj1x = xs[2 * j1], xj1y = xs[2 * j1 + 1];

  h2 Z2;
  Z2.x = Z2.y = (_Float16)0;

  // ---- Fused phase: scores + gate for 8 pairs per 16B KP load.
  float sc[8];  // [set*4 + {q0ka,q0kb,q1ka,q1kb}]
  float gt[8];
#pragma unroll
  for (int z = 0; z < 8; ++z) { sc[z] = 0.f; gt[z] = bc2; }
  const h8* kptr = KP + tid;
  h8 kbuf[8];
#pragma unroll
  for (int p = 0; p < 8; ++p) kbuf[p] = kptr[p * (NN / 2)];
  for (int ub = 0; ub < HH / 2; ub += 8) {
#pragma unroll
    for (int p = 0; p < 8; ++p) {
      const int u = ub + p;
      h8 kp = kbuf[p];
      // prefetch distance 8; final chunk over-reads into VP region (unused)
      kbuf[p] = kptr[(u + 8) * (NN / 2)];
      h2 ka, kb, pj0, pj1, cc;
      ka.x = kp[0]; ka.y = kp[1];
      kb.x = kp[2]; kb.y = kp[3];
      pj0.x = kp[4]; pj0.y = kp[5];
      pj1.x = kp[6]; pj1.y = kp[7];
      cc = ccs[u];
#pragma unroll
      for (int s = 0; s < 2; ++s) {
        h8 qp = qps[s][u];
        h2 q0, q1, pi0, pi1;
        q0.x = qp[0]; q0.y = qp[1];
        q1.x = qp[2]; q1.y = qp[3];
        pi0.x = qp[4]; pi0.y = qp[5];
        pi1.x = qp[6]; pi1.y = qp[7];
        sc[4 * s + 0] = fdot2(q0, ka, sc[4 * s + 0]);
        sc[4 * s + 1] = fdot2(q0, kb, sc[4 * s + 1]);
        sc[4 * s + 2] = fdot2(q1, ka, sc[4 * s + 2]);
        sc[4 * s + 3] = fdot2(q1, kb, sc[4 * s + 3]);
        h2 t00 = __builtin_elementwise_max(pi0 - pj0, Z2);
        h2 t01 = __builtin_elementwise_max(pi0 - pj1, Z2);
        h2 t10 = __builtin_elementwise_max(pi1 - pj0, Z2);
        h2 t11 = __builtin_elementwise_max(pi1 - pj1, Z2);
        gt[4 * s + 0] = fdot2(t00, cc, gt[4 * s + 0]);
        gt[4 * s + 1] = fdot2(t01, cc, gt[4 * s + 1]);
        gt[4 * s + 2] = fdot2(t10, cc, gt[4 * s + 2]);
        gt[4 * s + 3] = fdot2(t11, cc, gt[4 * s + 3]);
      }
    }
  }
  // q pre-scaled; softmax without max-shift (scores ~N(0,1), exp safe).
  float e[8];
#pragma unroll
  for (int z = 0; z < 8; ++z) e[z] = __expf(sc[z]);
  {
    h4 wA, wB;
    wA[0] = (_Float16)e[0]; wA[1] = (_Float16)e[1];
    wA[2] = (_Float16)e[2]; wA[3] = (_Float16)e[3];
    wB[0] = (_Float16)e[4]; wB[1] = (_Float16)e[5];
    wB[2] = (_Float16)e[6]; wB[3] = (_Float16)e[7];
    wspA[tid] = wA;
    wspB[tid] = wB;
  }
  // per-row l, dx, dy (row r: e[2r], e[2r+1] = j0, j1)
  float lr[4], dxr[4], dyr[4];
#pragma unroll
  for (int r = 0; r < 4; ++r) {
    const float w0 = e[2 * r] * gt[2 * r];
    const float w1 = e[2 * r + 1] * gt[2 * r + 1];
    lr[r] = e[2 * r] + e[2 * r + 1];
    dxr[r] = fmaf(w0, xix[r] - xj0x, w1 * (xix[r] - xj1x));
    dyr[r] = fmaf(w0, xiy[r] - xj0y, w1 * (xiy[r] - xj1y));
  }
#pragma unroll
  for (int off = 32; off > 0; off >>= 1) {
#pragma unroll
    for (int r = 0; r < 4; ++r) {
      lr[r] += __shfl_down(lr[r], off);
      dxr[r] += __shfl_down(dxr[r], off);
      dyr[r] += __shfl_down(dyr[r], off);
    }
  }
  if (lane == 0) {
#pragma unroll
    for (int r = 0; r < 4; ++r) {
      red[r][wave] = lr[r];
      red[4 + r][wave] = dxr[r];
      red[8 + r][wave] = dyr[r];
    }
  }

  // ---- Phase 2 (NO barrier): agg_h UNNORMALIZED, 8-deep prefetch on VP.
  //      Wave w consumes only the wspA/wspB range it wrote itself.
  {
    const int j4b = wave * 32;
    const h8* wA8 = (const h8*)wspA;  // two wspA entries per 16B
    const h8* wB8 = (const h8*)wspB;
    const h8* vptr = VP + j4b * (HH / 2) + lane;
    h8 vbuf[8];
#pragma unroll
    for (int p = 0; p < 8; ++p) vbuf[p] = vptr[p * (HH / 2)];
    float a0x = 0.f, a0y = 0.f, a1x = 0.f, a1y = 0.f;
    float a2x = 0.f, a2y = 0.f, a3x = 0.f, a3y = 0.f;
    for (int jb = 0; jb < 32; jb += 8) {
#pragma unroll
      for (int p = 0; p < 8; ++p) {
        const int j4 = j4b + jb + p;
        h8 vv = vbuf[p];
        // prefetch distance 8; tail over-reads past VP (Wc2/pad) — unused.
        vbuf[p] = vptr[(jb + 8 + p) * (HH / 2)];
        h8 wjA = wA8[j4];
        h8 wjB = wB8[j4];
        h2 v0a, v1a, v0b, v1b;
        v0a.x = vv[0]; v0a.y = vv[1];
        v1a.x = vv[2]; v1a.y = vv[3];
        v0b.x = vv[4]; v0b.y = vv[5];
        v1b.x = vv[6]; v1b.y = vv[7];
        h2 w0a, w1a, w0b, w1b;
        w0a.x = wjA[0]; w0a.y = wjA[1];
        w1a.x = wjA[2]; w1a.y = wjA[3];
        w0b.x = wjA[4]; w0b.y = wjA[5];
        w1b.x = wjA[6]; w1b.y = wjA[7];
        a0x = fdot2(w0a, v0a, a0x);
        a0x = fdot2(w0b, v0b, a0x);
        a0y = fdot2(w0a, v1a, a0y);
        a0y = fdot2(w0b, v1b, a0y);
        a1x = fdot2(w1a, v0a, a1x);
        a1x = fdot2(w1b, v0b, a1x);
        a1y = fdot2(w1a, v1a, a1y);
        a1y = fdot2(w1b, v1b, a1y);
        h2 w2a, w3a, w2b, w3b;
        w2a.x = wjB[0]; w2a.y = wjB[1];
        w3a.x = wjB[2]; w3a.y = wjB[3];
        w2b.x = wjB[4]; w2b.y = wjB[5];
        w3b.x = wjB[6]; w3b.y = wjB[7];
        a2x = fdot2(w2a, v0a, a2x);
        a2x = fdot2(w2b, v0b, a2x);
        a2y = fdot2(w2a, v1a, a2y);
        a2y = fdot2(w2b, v1b, a2y);
        a3x = fdot2(w3a, v0a, a3x);
        a3x = fdot2(w3b, v0b, a3x);
        a3y = fdot2(w3a, v1a, a3y);
        a3y = fdot2(w3b, v1b, a3y);
      }
    }
    part[wave][0][2 * lane] = a0x;
    part[wave][0][2 * lane + 1] = a0y;
    part[wave][1][2 * lane] = a1x;
    part[wave][1][2 * lane + 1] = a1y;
    part[wave][2][2 * lane] = a2x;
    part[wave][2][2 * lane + 1] = a2y;
    part[wave][3][2 * lane] = a3x;
    part[wave][3][2 * lane + 1] = a3y;
  }
  __syncthreads();  // single rendezvous: publishes part + red

  float inv[4];
#pragma unroll
  for (int r = 0; r < 4; ++r) {
    float s = 0.f;
#pragma unroll
    for (int w = 0; w < 8; ++w) s += red[r][w];
    inv[r] = 1.f / s;
  }

  if (tid == 0) {
#pragma unroll
    for (int r = 0; r < 4; ++r) {
      float DX = 0.f, DY = 0.f;
#pragma unroll
      for (int w = 0; w < 8; ++w) {
        DX += red[4 + r][w];
        DY += red[8 + r][w];
      }
      out[NN * HH + (i0 + r) * 2 + 0] = xix[r] + DX * inv[r];
      out[NN * HH + (i0 + r) * 2 + 1] = xiy[r] + DY * inv[r];
    }
  }

  {
    const int r = tid >> 7, c = tid & 127;
    float s = 0.f;
#pragma unroll
    for (int g = 0; g < 8; ++g) s += part[g][r][c];
    out[(i0 + r) * HH + c] = h[(i0 + r) * HH + c] + s * inv[r];
  }
}

// ------------------------------------------------------------- launch ------
extern "C" void kernel_launch(void* const* d_in, const int* in_sizes, int n_in,
                              void* d_out, int out_size, void* d_ws, size_t ws_size,
                              hipStream_t stream) {
  const float* h   = (const float*)d_in[0];
  const float* x   = (const float*)d_in[1];
  // d_in[2] = batch (int64) — unused (all zeros, reference ignores it)
  const float* Wq  = (const float*)d_in[3];
  const float* bq  = (const float*)d_in[4];
  const float* Wk  = (const float*)d_in[5];
  const float* bk  = (const float*)d_in[6];
  const float* Wv  = (const float*)d_in[7];
  const float* bv  = (const float*)d_in[8];
  const float* We1 = (const float*)d_in[9];
  const float* be1 = (const float*)d_in[10];
  const float* We2 = (const float*)d_in[11];
  const float* be2 = (const float*)d_in[12];
  const float* Wc  = (const float*)d_in[13];
  const float* bc  = (const float*)d_in[14];
  float* out = (float*)d_out;

  float* wsf = (float*)d_ws;
  float* q = wsf;                                   // N*H f32 (pre-scaled)
  _Float16* KP = (_Float16*)(wsf + NN * HH);        // [H/2][N/2] h8
  _Float16* VP = KP + (HH / 2) * (NN / 2) * 8;      // [N/4][H/2] h8
  float* Wc2 = (float*)(VP + (NN / 4) * (HH / 2) * 8);  // H (also prefetch pad)
  float* bc2 = Wc2 + HH;                            // 1

  qkv_kernel<<<257, 512, 0, stream>>>(h, x, Wq, bq, Wk, bk, Wv, bv, We1, We2,
                                      be2, Wc, bc, q, KP, VP, Wc2, bc2);
  attn_kernel<<<256, 512, 0, stream>>>(h, x, q, (const h8*)KP, (const h8*)VP,
                                       be1, Wc2, bc2, out);
}